// Round 6
// baseline (72.800 us; speedup 1.0000x reference)
//
#include <hip/hip_runtime.h>

// ProjectWDepth: B=64, C=128, 256 pts/batch -> (64,128,32,32) fp32 BEV grid.
// Fused single kernel. Block = (batch, channel-octet), 512 threads.
// Threads 0..255 voxelize the batch's 256 points (recomputed per block, ~40
// VALU), atomicMax best-y per cell in LDS, scatter 8 channel values of
// matched points into an 8x1024 LDS tile, then ALL 512 threads stream the
// tile out as one contiguous 32 KB float4 burst (8 consecutive channel rows).
// LDS 36 KB -> 4 blocks/CU, 32 waves/CU; 1024 blocks = 4.0 blocks/CU exact.
#define NBATCH   64
#define NCHAN    128
#define NPTS     256
#define MAPS     32
#define NCELL    (MAPS * MAPS)   // 1024
#define HMAXV    14
#define CELLF    0.1f
#define CAMH     1.72f
#define OCT      8               // channels per block

__global__ __launch_bounds__(512) void fused_bev_kernel(
    const float* __restrict__ feats,   // (B, C, 256) fp32
    const float* __restrict__ depth,   // (B, 256)    fp32
    const float* __restrict__ cam,     // (3, 256)    fp32
    float* __restrict__ out)           // (B, C, 1024) fp32
{
    const int b  = blockIdx.x;         // batch
    const int c0 = blockIdx.y * OCT;   // first channel of this octet
    const int t  = threadIdx.x;        // 0..511

    __shared__ int   s_besty[NCELL];          // 4 KB
    __shared__ float s_tile[OCT * NCELL];     // 32 KB, channel-major

    // init (linear, conflict-free)
    s_besty[t] = -1;
    s_besty[t + 512] = -1;
    const float4 z4 = make_float4(0.f, 0.f, 0.f, 0.f);
    #pragma unroll
    for (int k = 0; k < 4; ++k)
        ((float4*)s_tile)[t + 512 * k] = z4;

    // ---- voxelize + feature fetch: threads 0..255 only ----
    float f[OCT];
    int cell = 0, yi = 0;
    bool valid = false;
    if (t < NPTS) {
        const float d  = depth[b * NPTS + t];
        const float cx = cam[t], cy = cam[NPTS + t], cz = cam[2 * NPTS + t];

        const float* __restrict__ fb = feats + ((size_t)b * NCHAN + c0) * NPTS;
        #pragma unroll
        for (int k = 0; k < OCT; ++k) f[k] = fb[k * NPTS + t];

        // Explicit _rn ops: no FMA contraction; must match numpy f32
        // bit-for-bit at floor/valid boundaries.
        const float px = __fmul_rn(d, cx);
        const float py = __fadd_rn(__fmul_rn(d, cy), CAMH);
        const float pz = __fmul_rn(d, cz);
        const int xi = (int)floorf(__fdiv_rn(px, CELLF)) + MAPS / 2;
        yi           = (int)floorf(__fdiv_rn(py, CELLF));
        const int zi = (int)floorf(__fdiv_rn(pz, CELLF)) + MAPS;
        valid = (xi >= 0) && (xi < MAPS) && (zi >= 0) && (zi < MAPS) && (yi < HMAXV);
        cell = valid ? (zi * MAPS + xi) : 0;
    }

    __syncthreads();                   // init visible
    if (valid) atomicMax(&s_besty[cell], yi);
    __syncthreads();

    // ---- scatter matched features into LDS tile ----
    if (valid && yi == s_besty[cell]) {   // highest occupied y in this cell
        #pragma unroll
        for (int k = 0; k < OCT; ++k)
            atomicAdd(&s_tile[k * NCELL + cell], f[k]);
    }
    __syncthreads();

    // ---- stream tile to global: 8 consecutive rows = one contiguous 32 KB ----
    float* __restrict__ ob = out + ((size_t)b * NCHAN + c0) * NCELL;
    #pragma unroll
    for (int k = 0; k < 4; ++k)
        ((float4*)ob)[t + 512 * k] = ((float4*)s_tile)[t + 512 * k];
}

extern "C" void kernel_launch(void* const* d_in, const int* in_sizes, int n_in,
                              void* d_out, int out_size, void* d_ws, size_t ws_size,
                              hipStream_t stream) {
    const float* feats = (const float*)d_in[0];  // (64,128,16,16) fp32
    const float* depth = (const float*)d_in[1];  // (64,1,16,16)   fp32
    const float* cam   = (const float*)d_in[2];  // (3,256)        fp32
    float* out = (float*)d_out;                  // (64,128,32,32) fp32

    fused_bev_kernel<<<dim3(NBATCH, NCHAN / OCT), 512, 0, stream>>>(feats, depth, cam, out);
}

// Round 8
// 72.031 us; speedup vs baseline: 1.0107x; 1.0107x over previous
//
#include <hip/hip_runtime.h>

// ProjectWDepth: B=64, C=128, 256 pts/batch -> (64,128,32,32) fp32 BEV grid.
// Fused single kernel (best-measured R5 structure: block = batch x channel-
// quad, 256 threads, 20 KB LDS, 2048 blocks = 8/CU) + nontemporal output
// stores: the 33.5 MB output is write-once/never-read, so skip L2
// write-allocate. Feature rows also loaded nontemporally (read-once).
// NOTE: __builtin_nontemporal_* requires a clang vector type, not HIP's
// float4 class -> use ext_vector_type(4).
#define NBATCH   64
#define NCHAN    128
#define NPTS     256
#define MAPS     32
#define NCELL    (MAPS * MAPS)   // 1024
#define HMAXV    14
#define CELLF    0.1f
#define CAMH     1.72f

typedef float vfloat4 __attribute__((ext_vector_type(4)));

__global__ __launch_bounds__(256) void fused_bev_kernel(
    const float* __restrict__ feats,   // (B, C, 256) fp32
    const float* __restrict__ depth,   // (B, 256)    fp32
    const float* __restrict__ cam,     // (3, 256)    fp32
    float* __restrict__ out)           // (B, C, 1024) fp32
{
    const int b  = blockIdx.x;   // batch
    const int cq = blockIdx.y;   // channel quad 0..31
    const int t  = threadIdx.x;  // 0..255

    __shared__ int   s_besty[NCELL];       // 4 KB
    __shared__ float s_tile[4][NCELL];     // 16 KB

    // init (stride-1: conflict-free)
    #pragma unroll
    for (int k = 0; k < 4; ++k) s_besty[t + 256 * k] = -1;
    const vfloat4 z4 = {0.f, 0.f, 0.f, 0.f};
    #pragma unroll
    for (int k = 0; k < 4; ++k)
        ((vfloat4*)&s_tile[k][0])[t] = z4;

    // ---- voxelize point t of batch b ----
    const float d  = depth[b * NPTS + t];
    const float cx = cam[t], cy = cam[NPTS + t], cz = cam[2 * NPTS + t];

    // feature rows for this channel quad (read-once -> nontemporal)
    const int c0 = cq * 4;
    const float* __restrict__ fb = feats + ((size_t)b * NCHAN + c0) * NPTS;
    const float f0 = __builtin_nontemporal_load(fb + t);
    const float f1 = __builtin_nontemporal_load(fb + NPTS + t);
    const float f2 = __builtin_nontemporal_load(fb + 2 * NPTS + t);
    const float f3 = __builtin_nontemporal_load(fb + 3 * NPTS + t);

    // Explicit _rn ops: no FMA contraction; must match numpy f32 bit-for-bit
    // at floor/valid boundaries.
    const float px = __fmul_rn(d, cx);
    const float py = __fadd_rn(__fmul_rn(d, cy), CAMH);
    const float pz = __fmul_rn(d, cz);
    const int xi = (int)floorf(__fdiv_rn(px, CELLF)) + MAPS / 2;
    const int yi = (int)floorf(__fdiv_rn(py, CELLF));
    const int zi = (int)floorf(__fdiv_rn(pz, CELLF)) + MAPS;
    const bool valid = (xi >= 0) && (xi < MAPS) && (zi >= 0) && (zi < MAPS) && (yi < HMAXV);
    const int cell = valid ? (zi * MAPS + xi) : 0;

    __syncthreads();                       // init visible
    if (valid) atomicMax(&s_besty[cell], yi);
    __syncthreads();

    // ---- scatter matched features into the LDS tile ----
    if (valid && yi == s_besty[cell]) {    // highest occupied y in this cell
        atomicAdd(&s_tile[0][cell], f0);
        atomicAdd(&s_tile[1][cell], f1);
        atomicAdd(&s_tile[2][cell], f2);
        atomicAdd(&s_tile[3][cell], f3);
    }
    __syncthreads();

    // ---- stream tile to global: nontemporal float4 (write-once stream) ----
    float* __restrict__ ob = out + ((size_t)b * NCHAN + c0) * NCELL;
    #pragma unroll
    for (int k = 0; k < 4; ++k) {
        const vfloat4 v = ((vfloat4*)&s_tile[k][0])[t];
        __builtin_nontemporal_store(v, (vfloat4*)(ob + (size_t)k * NCELL) + t);
    }
}

extern "C" void kernel_launch(void* const* d_in, const int* in_sizes, int n_in,
                              void* d_out, int out_size, void* d_ws, size_t ws_size,
                              hipStream_t stream) {
    const float* feats = (const float*)d_in[0];  // (64,128,16,16) fp32
    const float* depth = (const float*)d_in[1];  // (64,1,16,16)   fp32
    const float* cam   = (const float*)d_in[2];  // (3,256)        fp32
    float* out = (float*)d_out;                  // (64,128,32,32) fp32

    fused_bev_kernel<<<dim3(NBATCH, NCHAN / 4), 256, 0, stream>>>(feats, depth, cam, out);
}